// Round 12
// baseline (181.171 us; speedup 1.0000x reference)
//
#include <hip/hip_runtime.h>
#include <math.h>

#define D 256
#define MARGIN 0.075f
#define MAXM 96   // max members per label tracked (P(overflow) ~ 0 for lambda≈13)
#define NBIN 8192  // conf in [0,1) -> u>>17 < 8128; per-block LDS hist = 32KB

typedef __bf16 bf8_t __attribute__((ext_vector_type(8)));
typedef float f4_t __attribute__((ext_vector_type(4)));
typedef unsigned long long ull;

#define AS1 __attribute__((address_space(1)))
#define AS3 __attribute__((address_space(3)))
static __device__ __forceinline__ void gload_lds16(const void* g, void* s) {
    __builtin_amdgcn_global_load_lds((const AS1 unsigned int*)g, (AS3 unsigned int*)s, 16, 0, 0);
}

#define ALOADU(p) __hip_atomic_load((p), __ATOMIC_RELAXED, __HIP_MEMORY_SCOPE_AGENT)
#define ASTOREU(p, v) __hip_atomic_store((p), (v), __ATOMIC_RELAXED, __HIP_MEMORY_SCOPE_AGENT)

// drain this wave's vmem ops (cheap; NO L2 writeback unlike __threadfence).
#define VDRAIN() asm volatile("s_waitcnt vmcnt(0)" ::: "memory")

// Hard-won structural rules (r6-r11):
//  * NO inter-block spin/cooperative barriers at the pipeline head: the
//    harness's 268MB poison-fill overlaps our head kernels and occupies CU
//    slots; co-residency fails and spins stall ~45us regardless of spin
//    mechanism (r8 load-poll == r10 RMW-poll). Redundant per-block compute
//    beats communication (r11: k_histsel 45.5 -> off the top-5).
//  * Arrive-counter EXIT-style tails (non-last blocks exit) are immune.
//  * k_fused must stay at VGPR=64: +4 VGPR crosses the HW quantum
//    (waves/SIMD 8->4) and costs 1.5x (r6, r9).

static __device__ __forceinline__ unsigned short f2bf(float x) {
    unsigned u = __float_as_uint(x);
    unsigned r = (u + 0x7fffu + ((u >> 16) & 1u)) >> 16;  // RNE
    return (unsigned short)r;
}

// min-reduction encoding: store cm = max(~bits(x)); init 0 = empty; decode
// 0 -> +inf, else x = ~cm. Valid for x >= 0.
static __device__ __forceinline__ float dec_min(unsigned cm) {
    return (cm == 0u) ? __builtin_inff() : __uint_as_float(~cm);
}

// DPP row_shl reductions over a 16-lane group; result in the LOWEST lane.
static __device__ __forceinline__ float rmin16(float v) {
    int s;
    s = __builtin_amdgcn_update_dpp(__float_as_int(v), __float_as_int(v), 0x101, 0xF, 0xF, false);
    v = fminf(v, __int_as_float(s));
    s = __builtin_amdgcn_update_dpp(__float_as_int(v), __float_as_int(v), 0x102, 0xF, 0xF, false);
    v = fminf(v, __int_as_float(s));
    s = __builtin_amdgcn_update_dpp(__float_as_int(v), __float_as_int(v), 0x104, 0xF, 0xF, false);
    v = fminf(v, __int_as_float(s));
    s = __builtin_amdgcn_update_dpp(__float_as_int(v), __float_as_int(v), 0x108, 0xF, 0xF, false);
    v = fminf(v, __int_as_float(s));
    return v;
}

// ---------------------------------------------------------------------------
// FUSED hist + scan + selection + boundary — ZERO cross-block waiting (r11).
// Every block redundantly histograms the FULL conf array (131KB, L2-resident)
// into its own 32KB LDS hist and computes b16/need/cgt independently.
// Boundary resolve: exit-style last-block tail (fill-gating immune).
// ctrl: [5]=gt slot ctr, [6]=cand ctr, [11]=done ctr.
__global__ __launch_bounds__(1024) void k_histsel(const float* __restrict__ conf, int n,
                                                  unsigned* __restrict__ ctrl, int ksel,
                                                  int* __restrict__ idx_sel,
                                                  ull* __restrict__ cand) {
    __shared__ __align__(16) unsigned shist[NBIN];   // 32KB
    __shared__ __align__(16) char aux[16384];        // part[] then scand[] overlay
    unsigned* part = (unsigned*)aux;                 // [1024] (scan phase)
    int t = threadIdx.x;

    for (int b = t; b < NBIN; b += 1024) shist[b] = 0u;
    __syncthreads();
    // full-array histogram (grid-stride over ALL of conf, every block)
    for (int i = t; i < n; i += 1024) {
        unsigned b = __float_as_uint(conf[i]) >> 17;
        if (b > NBIN - 1u) b = NBIN - 1u;
        atomicAdd(&shist[b], 1u);
    }
    __syncthreads();

    // suffix-scan: bin with count(>bin) < ksel <= count(>=bin)
    unsigned k = (unsigned)ksel;
    unsigned loc[8];
    unsigned s = 0;
    #pragma unroll
    for (int b = 0; b < 8; b++) { loc[b] = shist[t * 8 + b]; s += loc[b]; }
    part[t] = s;
    __syncthreads();
    for (int off = 1; off < 1024; off <<= 1) {
        unsigned v = (t + off < 1024) ? part[t + off] : 0u;
        __syncthreads();
        part[t] += v;
        __syncthreads();
    }
    __shared__ int schunk;
    __shared__ unsigned sbin, sneed, scgt;
    if (part[t] >= k && (t == 1023 || part[t + 1] < k)) schunk = t;
    __syncthreads();
    int c = schunk;
    if (t == c) {
        unsigned cum = (c == 1023) ? 0u : part[c + 1];
        int bin = 0; unsigned rem = 1;
        #pragma unroll
        for (int b = 7; b >= 0; b--) {
            unsigned h = loc[b];
            if (cum + h >= k) { bin = c * 8 + b; rem = k - cum; break; }
            cum += h;
        }
        sbin = (unsigned)bin; sneed = rem; scgt = k - rem;
    }
    __syncthreads();
    unsigned b16 = sbin, need = sneed, cgt = scgt;

    // selection on this block's own slice (set order irrelevant to the loss)
    int i = blockIdx.x * 1024 + t;
    if (i < n) {
        unsigned u = __float_as_uint(conf[i]);
        unsigned tb = u >> 17;
        if (tb > NBIN - 1u) tb = NBIN - 1u;
        if (tb > b16) {
            unsigned pos = atomicAdd(&ctrl[5], 1u);
            idx_sel[pos] = i;   // consumed only by next kernel
        } else if (tb == b16) {
            unsigned pos = atomicAdd(&ctrl[6], 1u);
            ASTOREU(&cand[pos], ((ull)u << 32) | (unsigned)i);
        }
    }
    VDRAIN();
    __syncthreads();   // this block's atomics/stores globally complete
    __shared__ int lastf;
    if (t == 0) lastf = (atomicAdd(&ctrl[11], 1u) == gridDim.x - 1) ? 1 : 0;
    __syncthreads();
    if (!lastf) return;

    // boundary bin (last-arriving block): rank by (value desc, index asc) —
    // exact jax.lax.top_k order. need/cgt are block-local (redundant scan).
    ull* scand = (ull*)aux;    // overlay (part[] is dead)
    int M = (int)atomicAdd(&ctrl[6], 0u);   // RMW read: always fresh
    if (M <= 2048) {
        for (int j = t; j < M; j += 1024) scand[j] = ALOADU(&cand[j]);
        __syncthreads();
        for (int j = t; j < M; j += 1024) {
            ull cj = scand[j];
            unsigned uj = (unsigned)(cj >> 32);
            unsigned rank = 0;
            for (int m = 0; m < M; m++) {
                ull cm = scand[m];
                unsigned um = (unsigned)(cm >> 32);
                if (um > uj || (um == uj && cm < cj)) rank++;
            }
            if (rank < need) idx_sel[cgt + rank] = (int)(unsigned)(cj & 0xFFFFFFFFu);
        }
    } else {
        for (int j = t; j < M; j += 1024) {
            ull cj = ALOADU(&cand[j]);
            unsigned uj = (unsigned)(cj >> 32);
            unsigned rank = 0;
            for (int m = 0; m < M; m++) {
                ull cm = ALOADU(&cand[m]);
                unsigned um = (unsigned)(cm >> 32);
                if (um > uj || (um == uj && cm < cj)) rank++;
            }
            if (rank < need) idx_sel[cgt + rank] = (int)(unsigned)(cj & 0xFFFFFFFFu);
        }
    }
}

// ---------------------------------------------------------------------------
// FUSED gather + hardpos — NO barrier (phase B reads only idx_sel/tags/emb,
// i.e. prev-kernel + input data; it never touches phase A's outputs).
// 512 blocks x 256. Phase A: grid-stride gather (ebf/sqn/lsel/labhist for
// the LATER kernels; padding rows sqn=+INF). Phase B: block L rebuilds label
// L's member list by SCANNING tags[idx_sel[j]] (redundancy > communication,
// r11 lesson), loads member rows from emb, converts with the BIT-IDENTICAL
// f2bf + 64-lane shfl_down sqn reduce, and runs the unchanged pairwise loop.
// hp values are pair-independent maxima -> member order irrelevant.
__global__ __launch_bounds__(256) void k_gatherpos(const float* __restrict__ emb,
                                                   const int* __restrict__ tags,
                                                   const int* __restrict__ idx_sel,
                                                   int ksel, int np,
                                                   unsigned short* __restrict__ ebf,
                                                   float* __restrict__ sqn,
                                                   int* __restrict__ lsel,
                                                   unsigned* __restrict__ labhist,
                                                   unsigned* __restrict__ hp_g) {
    int t = threadIdx.x;

    // -------- phase A: gather (grid-stride; writes consumed by k_fused/k_loss)
    int ngrp = np / 4;
    for (int g = blockIdx.x; g < ngrp; g += gridDim.x) {
        int j = g * 4 + (t >> 6);
        int lane = t & 63;
        if (j < ksel) {
            int src = idx_sel[j];
            float4 v = *(const float4*)&emb[(size_t)src * D + lane * 4];
            ushort4 o;
            o.x = f2bf(v.x); o.y = f2bf(v.y); o.z = f2bf(v.z); o.w = f2bf(v.w);
            *(ushort4*)&ebf[(size_t)j * D + lane * 4] = o;
            float s = v.x * v.x + v.y * v.y + v.z * v.z + v.w * v.w;
            for (int off = 32; off > 0; off >>= 1) s += __shfl_down(s, off);
            if (lane == 0) {
                sqn[j] = s; lsel[j] = tags[src];
                atomicAdd(&labhist[tags[src]], 1u);
            }
        } else {
            ushort4 z = {0, 0, 0, 0};
            *(ushort4*)&ebf[(size_t)j * D + (t & 63) * 4] = z;
            if ((t & 63) == 0) { sqn[j] = __builtin_inff(); lsel[j] = -1; }
        }
    }

    // -------- phase B: hard_pos^2 for label L = blockIdx (no dependency on A)
    int L = blockIdx.x;
    __shared__ unsigned short rows[MAXM * 256];   // 48KB
    __shared__ float lsqn[MAXM];
    __shared__ unsigned hpl[MAXM];
    __shared__ int memj[MAXM];
    __shared__ int memsrc[MAXM];
    __shared__ int scnt_;

    if (t == 0) scnt_ = 0;
    __syncthreads();
    for (int j = t; j < ksel; j += 256) {
        int src = idx_sel[j];
        if (tags[src] == L) {
            int slot = atomicAdd(&scnt_, 1);
            if (slot < MAXM) { memj[slot] = j; memsrc[slot] = src; }
        }
    }
    __syncthreads();
    int m = scnt_;
    if (m > MAXM) m = MAXM;
    if (m < 2) return;   // hp_g stays 0 (anchor invalid anyway)

    // load member rows from emb; convert bf16 + sqn EXACTLY like phase A
    int w = t >> 6, l = t & 63;
    for (int a = w; a < m; a += 4) {
        int src = memsrc[a];
        float4 v = *(const float4*)&emb[(size_t)src * D + l * 4];
        ushort4 o;
        o.x = f2bf(v.x); o.y = f2bf(v.y); o.z = f2bf(v.z); o.w = f2bf(v.w);
        *(ushort4*)&rows[a * 256 + l * 4] = o;
        float s = v.x * v.x + v.y * v.y + v.z * v.z + v.w * v.w;
        for (int off = 32; off > 0; off >>= 1) s += __shfl_down(s, off);
        if (l == 0) { lsqn[a] = s; hpl[a] = 0u; }
    }
    __syncthreads();

    int npair = m * (m - 1) / 2;
    for (int pidx = t; pidx < npair; pidx += 256) {
        int a = 0, rem = pidx;
        while (rem >= m - 1 - a) { rem -= m - 1 - a; a++; }
        int b = a + 1 + rem;
        const unsigned* ra = (const unsigned*)&rows[a * 256];
        const unsigned* rb = (const unsigned*)&rows[b * 256];
        float dot = 0.f;
        #pragma unroll 8
        for (int c = 0; c < 128; c++) {
            unsigned ua = ra[c], ub = rb[c];
            float a0 = __uint_as_float(ua << 16);
            float a1 = __uint_as_float(ua & 0xFFFF0000u);
            float b0 = __uint_as_float(ub << 16);
            float b1 = __uint_as_float(ub & 0xFFFF0000u);
            dot = fmaf(a0, b0, dot);
            dot = fmaf(a1, b1, dot);
        }
        float dsq = fmaxf(lsqn[a] + lsqn[b] - 2.f * dot, 0.f);
        unsigned bits = __float_as_uint(dsq);
        atomicMax(&hpl[a], bits);
        atomicMax(&hpl[b], bits);
    }
    __syncthreads();
    for (int a = t; a < m; a += 256) hp_g[memj[a]] = hpl[a];  // next-kernel consumer
}

// ---------------------------------------------------------------------------
// SINGLE-PASS fused MFMA GEMM + mining on SQUARED distances.
// EXACT r7 structure (measured 45.1us, VGPR 64). DO NOT add code here
// (r6/r9: +4 VGPR crosses the HW quantum, waves/SIMD 8->4, 1.5x cost).
__global__ __launch_bounds__(256, 3) void k_fused(const unsigned short* __restrict__ Ebf,
                                                  const float* __restrict__ sqn,
                                                  const int* __restrict__ lsel,
                                                  const unsigned* __restrict__ hp_g,
                                                  unsigned* __restrict__ nm_g,
                                                  unsigned* __restrict__ shn_g,
                                                  int np, int nb, int ksel) {
    int rem = blockIdx.x, bi = 0;
    while (rem >= nb - bi) { rem -= nb - bi; bi++; }
    int bj = bi + rem;
    int i0 = bi * 128, j0 = bj * 128;
    bool diag = (bi == bj);

    __shared__ __align__(16) char smem[32768];
    char* ldsA = smem;
    char* ldsB = smem + 16384;

    int t = threadIdx.x;
    int w = t >> 6, l = t & 63;
    int wm = w & 1, wn = w >> 1;
    int lr = l & 15, lq = l >> 4;
    int r7 = lr & 7, rh = lr >> 3;

    int dr = l >> 3;
    int sg = (l & 7) ^ dr;
    const unsigned short* gA = Ebf + (size_t)(i0 + dr) * D + sg * 8;
    const unsigned short* gB = Ebf + (size_t)(j0 + dr) * D + sg * 8;

    f4_t zero = {0.f, 0.f, 0.f, 0.f};
    f4_t acc[4][4];
    #pragma unroll
    for (int p = 0; p < 4; p++)
        #pragma unroll
        for (int q = 0; q < 4; q++) acc[p][q] = zero;

    for (int k0 = 0; k0 < D; k0 += 64) {
        #pragma unroll
        for (int c = 0; c < 4; c++) {
            int R0 = w * 32 + c * 8;
            gload_lds16(gA + (size_t)R0 * D + k0, ldsA + R0 * 128);
            gload_lds16(gB + (size_t)R0 * D + k0, ldsB + R0 * 128);
        }
        __syncthreads();
        #pragma unroll
        for (int ks8 = 0; ks8 < 8; ks8 += 4) {
            bf8_t a[4], b[4];
            #pragma unroll
            for (int p = 0; p < 4; p++) {
                int off = ((wm * 8 + p * 2 + rh) << 10) + ((r7 * 8 + ((ks8 + lq) ^ r7)) << 4);
                a[p] = *(const bf8_t*)(ldsA + off);
            }
            #pragma unroll
            for (int q = 0; q < 4; q++) {
                int off = ((wn * 8 + q * 2 + rh) << 10) + ((r7 * 8 + ((ks8 + lq) ^ r7)) << 4);
                b[q] = *(const bf8_t*)(ldsB + off);
            }
            #pragma unroll
            for (int p = 0; p < 4; p++)
                #pragma unroll
                for (int q = 0; q < 4; q++)
                    acc[p][q] = __builtin_amdgcn_mfma_f32_16x16x32_bf16(a[p], b[q], acc[p][q], 0, 0, 0);
        }
        __syncthreads();
    }

    // stage sqn / labels / hard_pos^2 into LDS (smem reuse after K-loop)
    float* sqnA = (float*)smem;
    float* sqnB = sqnA + 128;
    int* labA = (int*)(sqnB + 128);
    int* labB = labA + 128;
    float* hpA2 = (float*)(labB + 128);
    float* hpB2 = hpA2 + 128;
    if (t < 128) {
        sqnA[t] = sqn[i0 + t];
        labA[t] = lsel[i0 + t];
        hpA2[t] = __uint_as_float(hp_g[i0 + t]);
    } else {
        int u = t - 128;
        sqnB[u] = sqn[j0 + u];
        labB[u] = lsel[j0 + u];
        hpB2[u] = __uint_as_float(hp_g[j0 + u]);
    }
    __syncthreads();

    // squared distances; C/D map: col = lane&15, row = (lane>>4)*4+reg.
    // Padding rows have sqn=+INF -> dsq=+INF -> no-op in every min below.
    const float INF = __builtin_inff();
    float dsq[4][4][4];
    int colL[4], ljv[4];
    float sBv[4];
    #pragma unroll
    for (int q = 0; q < 4; q++) {
        colL[q] = wn * 64 + q * 16 + lr;
        ljv[q] = labB[colL[q]];
        sBv[q] = sqnB[colL[q]];
    }
    #pragma unroll
    for (int p = 0; p < 4; p++) {
        #pragma unroll
        for (int r = 0; r < 4; r++) {
            int rowL = wm * 64 + p * 16 + lq * 4 + r;
            float smi = sqnA[rowL];
            #pragma unroll
            for (int q = 0; q < 4; q++)
                dsq[p][q][r] = fmaxf(smi + sBv[q] - 2.f * acc[p][q][r], 0.f);
        }
    }

    // row-direction: neg_min + semi-hard min (DPP row_shl; result in lr==0)
    #pragma unroll
    for (int p = 0; p < 4; p++) {
        #pragma unroll
        for (int r = 0; r < 4; r++) {
            int rowL = wm * 64 + p * 16 + lq * 4 + r;
            int li = labA[rowL];
            float hpr = hpA2[rowL];
            float nmv = INF, smv = INF;
            #pragma unroll
            for (int q = 0; q < 4; q++) {
                float d = dsq[p][q][r];
                if (ljv[q] != li) {
                    nmv = fminf(nmv, d);
                    if (d > hpr) smv = fminf(smv, d);
                }
            }
            nmv = rmin16(nmv);
            smv = rmin16(smv);
            if (lr == 0) {
                if (nmv < INF) atomicMax(&nm_g[i0 + rowL], ~__float_as_uint(nmv));
                if (smv < INF) atomicMax(&shn_g[i0 + rowL], ~__float_as_uint(smv));
            }
        }
    }

    // column-direction (mirror; off-diagonal blocks only)
    if (!diag) {
        #pragma unroll
        for (int q = 0; q < 4; q++) {
            int lj = ljv[q];
            float hpc = hpB2[colL[q]];
            float nmv = INF, smv = INF;
            #pragma unroll
            for (int p = 0; p < 4; p++)
                #pragma unroll
                for (int r = 0; r < 4; r++) {
                    int rowL = wm * 64 + p * 16 + lq * 4 + r;
                    float d = dsq[p][q][r];
                    if (labA[rowL] != lj) {
                        nmv = fminf(nmv, d);
                        if (d > hpc) smv = fminf(smv, d);
                    }
                }
            nmv = fminf(nmv, __shfl_xor(nmv, 16));
            nmv = fminf(nmv, __shfl_xor(nmv, 32));
            smv = fminf(smv, __shfl_xor(smv, 16));
            smv = fminf(smv, __shfl_xor(smv, 32));
            if (lq == 0) {
                if (nmv < INF) atomicMax(&nm_g[j0 + colL[q]], ~__float_as_uint(nmv));
                if (smv < INF) atomicMax(&shn_g[j0 + colL[q]], ~__float_as_uint(smv));
            }
        }
    }
}

// ---------------------------------------------------------------------------
// loss reduction + final output (last finished block writes out; ctrl[7])
__global__ __launch_bounds__(256) void k_loss(const unsigned* __restrict__ hp,
                                              const unsigned* __restrict__ nm,
                                              const unsigned* __restrict__ shn,
                                              const int* __restrict__ lsel,
                                              const unsigned* __restrict__ labhist,
                                              int ksel, float* __restrict__ fsums,
                                              unsigned* __restrict__ ctrl,
                                              float* __restrict__ out) {
    __shared__ float ssum[256], scnt[256];
    int t = threadIdx.x;
    int i = blockIdx.x * 256 + t;
    float sum = 0.f, cnt = 0.f;
    if (i < ksel) {
        int li = lsel[i];
        unsigned h = labhist[li];
        bool valid = (h >= 2u) && ((unsigned)ksel > h);
        if (valid) {
            float hp2 = __uint_as_float(hp[i]);
            float nm2 = dec_min(nm[i]);
            float sh2 = dec_min(shn[i]);
            float hn2 = isinf(sh2) ? nm2 : sh2;
            sum = fmaxf(sqrtf(hp2) - sqrtf(hn2) + MARGIN, 0.f);
            cnt = 1.f;
        }
    }
    ssum[t] = sum; scnt[t] = cnt;
    __syncthreads();
    for (int off = 128; off > 0; off >>= 1) {
        if (t < off) { ssum[t] += ssum[t + off]; scnt[t] += scnt[t + off]; }
        __syncthreads();
    }
    if (t == 0) {
        atomicAdd(&fsums[0], ssum[0]);
        atomicAdd(&fsums[1], scnt[0]);
        VDRAIN();
        unsigned done = atomicAdd(&ctrl[7], 1u);
        if (done == gridDim.x - 1) {
            float s = atomicAdd(&fsums[0], 0.f);
            float c = atomicAdd(&fsums[1], 0.f);
            out[0] = (c > 0.f) ? (s / fmaxf(c, 1.f)) : 0.f;
        }
    }
}

__global__ void k_wsfail(float* out, float code) { out[0] = code; }

// ---------------------------------------------------------------------------
static inline size_t align_up(size_t x, size_t a) { return (x + a - 1) & ~(a - 1); }

extern "C" void kernel_launch(void* const* d_in, const int* in_sizes, int n_in,
                              void* d_out, int out_size, void* d_ws, size_t ws_size,
                              hipStream_t stream) {
    const float* emb  = (const float*)d_in[0];
    const int*   tags = (const int*)d_in[1];
    const float* conf = (const float*)d_in[2];
    float* out = (float*)d_out;

    int n = in_sizes[2];                        // 32768
    int ksel = (int)(0.2 * (double)n);          // 6553
    int np = ((ksel + 127) / 128) * 128;        // 6656
    int nb = np / 128;                          // 52
    int nlab = 512;                             // tags in [0,500)

    // ---- zero-init region (single hipMemsetAsync covers all of it) ----
    size_t off = 0;
    size_t o_ctrl = off; off = align_up(off + 32 * sizeof(unsigned), 256);
    size_t o_fs   = off; off = align_up(off + 8 * sizeof(float), 256);
    size_t o_lh   = off; off = align_up(off + (size_t)nlab * 4, 256);
    size_t o_hp   = off; off = align_up(off + (size_t)np * 4, 256);
    size_t o_nm   = off; off = align_up(off + (size_t)np * 4, 256);
    size_t o_shn  = off; off = align_up(off + (size_t)np * 4, 256);
    size_t zero_bytes = off;
    // ---- non-zeroed ----
    size_t o_idx  = off; off = align_up(off + (size_t)ksel * 4, 256);
    size_t o_cand = off; off = align_up(off + (size_t)n * 8, 256);
    size_t o_lab  = off; off = align_up(off + (size_t)np * 4, 256);
    size_t o_sqn  = off; off = align_up(off + (size_t)np * 4, 256);
    size_t o_ebf  = off; off = align_up(off + (size_t)np * D * 2, 256);

    if (ws_size < off) {
        k_wsfail<<<1, 1, 0, stream>>>(out, -(float)(ws_size >> 20));
        return;
    }

    char* ws = (char*)d_ws;
    unsigned*       ctrl    = (unsigned*)(ws + o_ctrl);
    float*          fsums   = (float*)(ws + o_fs);
    unsigned*       labhist = (unsigned*)(ws + o_lh);
    unsigned*       hp_g    = (unsigned*)(ws + o_hp);
    unsigned*       nm_g    = (unsigned*)(ws + o_nm);
    unsigned*       shn_g   = (unsigned*)(ws + o_shn);
    int*            idx_sel = (int*)(ws + o_idx);
    ull*            cand    = (ull*)(ws + o_cand);
    int*            lsel    = (int*)(ws + o_lab);
    float*          sqn     = (float*)(ws + o_sqn);
    unsigned short* ebf     = (unsigned short*)(ws + o_ebf);

    hipMemsetAsync(d_ws, 0, zero_bytes, stream);
    int nhb = (n + 1023) / 1024;   // 32 blocks, fully independent (no spin)
    k_histsel<<<nhb, 1024, 0, stream>>>(conf, n, ctrl, ksel, idx_sel, cand);
    k_gatherpos<<<nlab, 256, 0, stream>>>(emb, tags, idx_sel, ksel, np, ebf, sqn,
                                          lsel, labhist, hp_g);
    int ntri = nb * (nb + 1) / 2;
    k_fused<<<ntri, 256, 0, stream>>>(ebf, sqn, lsel, hp_g, nm_g, shn_g, np, nb, ksel);
    k_loss<<<(ksel + 255) / 256, 256, 0, stream>>>(hp_g, nm_g, shn_g, lsel, labhist,
                                                   ksel, fsums, ctrl, out);
}

// Round 13
// 172.230 us; speedup vs baseline: 1.0519x; 1.0519x over previous
//
#include <hip/hip_runtime.h>
#include <math.h>

#define D 256
#define MARGIN 0.075f
#define MAXM 96   // max members per label tracked (P(overflow) ~ 0 for lambda≈13)
#define NBIN 8192  // conf in [0,1) -> u>>17 < 8128; per-block LDS hist = 32KB

typedef __bf16 bf8_t __attribute__((ext_vector_type(8)));
typedef float f4_t __attribute__((ext_vector_type(4)));
typedef unsigned long long ull;

#define AS1 __attribute__((address_space(1)))
#define AS3 __attribute__((address_space(3)))
static __device__ __forceinline__ void gload_lds16(const void* g, void* s) {
    __builtin_amdgcn_global_load_lds((const AS1 unsigned int*)g, (AS3 unsigned int*)s, 16, 0, 0);
}

#define ALOADU(p) __hip_atomic_load((p), __ATOMIC_RELAXED, __HIP_MEMORY_SCOPE_AGENT)
#define ASTOREU(p, v) __hip_atomic_store((p), (v), __ATOMIC_RELAXED, __HIP_MEMORY_SCOPE_AGENT)

// drain this wave's vmem ops (cheap; NO L2 writeback unlike __threadfence).
#define VDRAIN() asm volatile("s_waitcnt vmcnt(0)" ::: "memory")

// Hard-won structural rules (r6-r12):
//  * NO inter-block spin/cooperative barriers at the pipeline head: the
//    harness's 268MB poison-fill overlaps our head kernels and occupies CU
//    slots; co-residency fails and spins stall ~45us regardless of spin
//    mechanism (r8 load-poll == r10 RMW-poll).
//  * Redundant per-block compute beats communication ONLY when the redundant
//    work is small + streaming (r11 histsel: won; r12 gatherpos with 3.4M
//    random tag-gathers: lost 8us).
//  * Arrive-counter EXIT-style tails (non-last blocks exit) are immune.
//  * k_fused must stay at VGPR=64: +4 VGPR crosses the HW quantum
//    (waves/SIMD 8->4) and costs 1.5x (r6, r9).

static __device__ __forceinline__ unsigned short f2bf(float x) {
    unsigned u = __float_as_uint(x);
    unsigned r = (u + 0x7fffu + ((u >> 16) & 1u)) >> 16;  // RNE
    return (unsigned short)r;
}

// min-reduction encoding: store cm = max(~bits(x)); init 0 = empty; decode
// 0 -> +inf, else x = ~cm. Valid for x >= 0.
static __device__ __forceinline__ float dec_min(unsigned cm) {
    return (cm == 0u) ? __builtin_inff() : __uint_as_float(~cm);
}

// DPP row_shl reductions over a 16-lane group; result in the LOWEST lane.
static __device__ __forceinline__ float rmin16(float v) {
    int s;
    s = __builtin_amdgcn_update_dpp(__float_as_int(v), __float_as_int(v), 0x101, 0xF, 0xF, false);
    v = fminf(v, __int_as_float(s));
    s = __builtin_amdgcn_update_dpp(__float_as_int(v), __float_as_int(v), 0x102, 0xF, 0xF, false);
    v = fminf(v, __int_as_float(s));
    s = __builtin_amdgcn_update_dpp(__float_as_int(v), __float_as_int(v), 0x104, 0xF, 0xF, false);
    v = fminf(v, __int_as_float(s));
    s = __builtin_amdgcn_update_dpp(__float_as_int(v), __float_as_int(v), 0x108, 0xF, 0xF, false);
    v = fminf(v, __int_as_float(s));
    return v;
}

// ---------------------------------------------------------------------------
// FUSED hist + scan + selection + boundary — ZERO cross-block waiting (r11).
// Every block redundantly histograms the FULL conf array (131KB, L2-resident)
// into its own 32KB LDS hist and computes b16/need/cgt independently.
// Boundary resolve: exit-style last-block tail (fill-gating immune).
// ctrl: [5]=gt slot ctr, [6]=cand ctr, [11]=done ctr.
__global__ __launch_bounds__(1024) void k_histsel(const float* __restrict__ conf, int n,
                                                  unsigned* __restrict__ ctrl, int ksel,
                                                  int* __restrict__ idx_sel,
                                                  ull* __restrict__ cand) {
    __shared__ __align__(16) unsigned shist[NBIN];   // 32KB
    __shared__ __align__(16) char aux[16384];        // part[] then scand[] overlay
    unsigned* part = (unsigned*)aux;                 // [1024] (scan phase)
    int t = threadIdx.x;

    for (int b = t; b < NBIN; b += 1024) shist[b] = 0u;
    __syncthreads();
    // full-array histogram (grid-stride over ALL of conf, every block)
    for (int i = t; i < n; i += 1024) {
        unsigned b = __float_as_uint(conf[i]) >> 17;
        if (b > NBIN - 1u) b = NBIN - 1u;
        atomicAdd(&shist[b], 1u);
    }
    __syncthreads();

    // suffix-scan: bin with count(>bin) < ksel <= count(>=bin)
    unsigned k = (unsigned)ksel;
    unsigned loc[8];
    unsigned s = 0;
    #pragma unroll
    for (int b = 0; b < 8; b++) { loc[b] = shist[t * 8 + b]; s += loc[b]; }
    part[t] = s;
    __syncthreads();
    for (int off = 1; off < 1024; off <<= 1) {
        unsigned v = (t + off < 1024) ? part[t + off] : 0u;
        __syncthreads();
        part[t] += v;
        __syncthreads();
    }
    __shared__ int schunk;
    __shared__ unsigned sbin, sneed, scgt;
    if (part[t] >= k && (t == 1023 || part[t + 1] < k)) schunk = t;
    __syncthreads();
    int c = schunk;
    if (t == c) {
        unsigned cum = (c == 1023) ? 0u : part[c + 1];
        int bin = 0; unsigned rem = 1;
        #pragma unroll
        for (int b = 7; b >= 0; b--) {
            unsigned h = loc[b];
            if (cum + h >= k) { bin = c * 8 + b; rem = k - cum; break; }
            cum += h;
        }
        sbin = (unsigned)bin; sneed = rem; scgt = k - rem;
    }
    __syncthreads();
    unsigned b16 = sbin, need = sneed, cgt = scgt;

    // selection on this block's own slice (set order irrelevant to the loss)
    int i = blockIdx.x * 1024 + t;
    if (i < n) {
        unsigned u = __float_as_uint(conf[i]);
        unsigned tb = u >> 17;
        if (tb > NBIN - 1u) tb = NBIN - 1u;
        if (tb > b16) {
            unsigned pos = atomicAdd(&ctrl[5], 1u);
            idx_sel[pos] = i;   // consumed only by next kernel
        } else if (tb == b16) {
            unsigned pos = atomicAdd(&ctrl[6], 1u);
            ASTOREU(&cand[pos], ((ull)u << 32) | (unsigned)i);
        }
    }
    VDRAIN();
    __syncthreads();   // this block's atomics/stores globally complete
    __shared__ int lastf;
    if (t == 0) lastf = (atomicAdd(&ctrl[11], 1u) == gridDim.x - 1) ? 1 : 0;
    __syncthreads();
    if (!lastf) return;

    // boundary bin (last-arriving block): rank by (value desc, index asc) —
    // exact jax.lax.top_k order. need/cgt are block-local (redundant scan).
    ull* scand = (ull*)aux;    // overlay (part[] is dead)
    int M = (int)atomicAdd(&ctrl[6], 0u);   // RMW read: always fresh
    if (M <= 2048) {
        for (int j = t; j < M; j += 1024) scand[j] = ALOADU(&cand[j]);
        __syncthreads();
        for (int j = t; j < M; j += 1024) {
            ull cj = scand[j];
            unsigned uj = (unsigned)(cj >> 32);
            unsigned rank = 0;
            for (int m = 0; m < M; m++) {
                ull cm = scand[m];
                unsigned um = (unsigned)(cm >> 32);
                if (um > uj || (um == uj && cm < cj)) rank++;
            }
            if (rank < need) idx_sel[cgt + rank] = (int)(unsigned)(cj & 0xFFFFFFFFu);
        }
    } else {
        for (int j = t; j < M; j += 1024) {
            ull cj = ALOADU(&cand[j]);
            unsigned uj = (unsigned)(cj >> 32);
            unsigned rank = 0;
            for (int m = 0; m < M; m++) {
                ull cm = ALOADU(&cand[m]);
                unsigned um = (unsigned)(cm >> 32);
                if (um > uj || (um == uj && cm < cj)) rank++;
            }
            if (rank < need) idx_sel[cgt + rank] = (int)(unsigned)(cj & 0xFFFFFFFFu);
        }
    }
}

// ---------------------------------------------------------------------------
// gather rows -> bf16, fp32 sq-norms, labels, label histogram + member lists.
// Padding rows: sqn=+INF (every distance to them +INF -> no-op in all mins).
__global__ __launch_bounds__(256) void k_gather(const float* __restrict__ emb,
                                                const int* __restrict__ tags,
                                                const int* __restrict__ idx_sel,
                                                int ksel, int np,
                                                unsigned short* __restrict__ ebf,
                                                float* __restrict__ sqn,
                                                int* __restrict__ lsel,
                                                unsigned* __restrict__ labhist,
                                                int* __restrict__ members) {
    int j = blockIdx.x * 4 + (threadIdx.x >> 6);
    int t = threadIdx.x & 63;
    if (j < ksel) {
        int src = idx_sel[j];
        float4 v = *(const float4*)&emb[(size_t)src * D + t * 4];
        ushort4 o;
        o.x = f2bf(v.x); o.y = f2bf(v.y); o.z = f2bf(v.z); o.w = f2bf(v.w);
        *(ushort4*)&ebf[(size_t)j * D + t * 4] = o;
        float s = v.x * v.x + v.y * v.y + v.z * v.z + v.w * v.w;
        for (int off = 32; off > 0; off >>= 1) s += __shfl_down(s, off);
        if (t == 0) {
            int lab = tags[src];
            sqn[j] = s; lsel[j] = lab;
            unsigned slot = atomicAdd(&labhist[lab], 1u);
            if (slot < MAXM) members[lab * MAXM + slot] = j;
        }
    } else if (j < np) {
        ushort4 z = {0, 0, 0, 0};
        *(ushort4*)&ebf[(size_t)j * D + t * 4] = z;
        if (t == 0) { sqn[j] = __builtin_inff(); lsel[j] = -1; }
    }
}

// ---------------------------------------------------------------------------
// hard_pos^2 per anchor from same-label pairs only (~13 members/label).
__global__ __launch_bounds__(256) void k_hardpos(const unsigned short* __restrict__ ebf,
                                                 const float* __restrict__ sqn,
                                                 const int* __restrict__ members,
                                                 const unsigned* __restrict__ labhist,
                                                 unsigned* __restrict__ hp_g) {
    int L = blockIdx.x;
    int t = threadIdx.x;
    int m = (int)labhist[L];
    if (m > MAXM) m = MAXM;
    if (m < 2) return;

    __shared__ unsigned short rows[MAXM * 256];
    __shared__ float lsqn[MAXM];
    __shared__ unsigned hpl[MAXM];
    __shared__ int ridx[MAXM];

    for (int a = t; a < m; a += 256) {
        int r = members[L * MAXM + a];
        ridx[a] = r; lsqn[a] = sqn[r]; hpl[a] = 0u;
    }
    __syncthreads();
    for (int e = t * 8; e < m * 256; e += 256 * 8) {
        int a = e >> 8, c = e & 255;
        *(uint4*)&rows[a * 256 + c] = *(const uint4*)&ebf[(size_t)ridx[a] * D + c];
    }
    __syncthreads();

    int npair = m * (m - 1) / 2;
    for (int pidx = t; pidx < npair; pidx += 256) {
        int a = 0, rem = pidx;
        while (rem >= m - 1 - a) { rem -= m - 1 - a; a++; }
        int b = a + 1 + rem;
        const unsigned* ra = (const unsigned*)&rows[a * 256];
        const unsigned* rb = (const unsigned*)&rows[b * 256];
        float dot = 0.f;
        #pragma unroll 8
        for (int c = 0; c < 128; c++) {
            unsigned ua = ra[c], ub = rb[c];
            float a0 = __uint_as_float(ua << 16);
            float a1 = __uint_as_float(ua & 0xFFFF0000u);
            float b0 = __uint_as_float(ub << 16);
            float b1 = __uint_as_float(ub & 0xFFFF0000u);
            dot = fmaf(a0, b0, dot);
            dot = fmaf(a1, b1, dot);
        }
        float dsq = fmaxf(lsqn[a] + lsqn[b] - 2.f * dot, 0.f);
        unsigned bits = __float_as_uint(dsq);
        atomicMax(&hpl[a], bits);
        atomicMax(&hpl[b], bits);
    }
    __syncthreads();
    for (int a = t; a < m; a += 256) hp_g[ridx[a]] = hpl[a];
}

// ---------------------------------------------------------------------------
// SINGLE-PASS fused MFMA GEMM + mining on SQUARED distances.
// EXACT r7 structure (measured 45.1us, VGPR 64). DO NOT add code here
// (r6/r9: +4 VGPR crosses the HW quantum, waves/SIMD 8->4, 1.5x cost).
__global__ __launch_bounds__(256, 3) void k_fused(const unsigned short* __restrict__ Ebf,
                                                  const float* __restrict__ sqn,
                                                  const int* __restrict__ lsel,
                                                  const unsigned* __restrict__ hp_g,
                                                  unsigned* __restrict__ nm_g,
                                                  unsigned* __restrict__ shn_g,
                                                  int np, int nb, int ksel) {
    int rem = blockIdx.x, bi = 0;
    while (rem >= nb - bi) { rem -= nb - bi; bi++; }
    int bj = bi + rem;
    int i0 = bi * 128, j0 = bj * 128;
    bool diag = (bi == bj);

    __shared__ __align__(16) char smem[32768];
    char* ldsA = smem;
    char* ldsB = smem + 16384;

    int t = threadIdx.x;
    int w = t >> 6, l = t & 63;
    int wm = w & 1, wn = w >> 1;
    int lr = l & 15, lq = l >> 4;
    int r7 = lr & 7, rh = lr >> 3;

    int dr = l >> 3;
    int sg = (l & 7) ^ dr;
    const unsigned short* gA = Ebf + (size_t)(i0 + dr) * D + sg * 8;
    const unsigned short* gB = Ebf + (size_t)(j0 + dr) * D + sg * 8;

    f4_t zero = {0.f, 0.f, 0.f, 0.f};
    f4_t acc[4][4];
    #pragma unroll
    for (int p = 0; p < 4; p++)
        #pragma unroll
        for (int q = 0; q < 4; q++) acc[p][q] = zero;

    for (int k0 = 0; k0 < D; k0 += 64) {
        #pragma unroll
        for (int c = 0; c < 4; c++) {
            int R0 = w * 32 + c * 8;
            gload_lds16(gA + (size_t)R0 * D + k0, ldsA + R0 * 128);
            gload_lds16(gB + (size_t)R0 * D + k0, ldsB + R0 * 128);
        }
        __syncthreads();
        #pragma unroll
        for (int ks8 = 0; ks8 < 8; ks8 += 4) {
            bf8_t a[4], b[4];
            #pragma unroll
            for (int p = 0; p < 4; p++) {
                int off = ((wm * 8 + p * 2 + rh) << 10) + ((r7 * 8 + ((ks8 + lq) ^ r7)) << 4);
                a[p] = *(const bf8_t*)(ldsA + off);
            }
            #pragma unroll
            for (int q = 0; q < 4; q++) {
                int off = ((wn * 8 + q * 2 + rh) << 10) + ((r7 * 8 + ((ks8 + lq) ^ r7)) << 4);
                b[q] = *(const bf8_t*)(ldsB + off);
            }
            #pragma unroll
            for (int p = 0; p < 4; p++)
                #pragma unroll
                for (int q = 0; q < 4; q++)
                    acc[p][q] = __builtin_amdgcn_mfma_f32_16x16x32_bf16(a[p], b[q], acc[p][q], 0, 0, 0);
        }
        __syncthreads();
    }

    // stage sqn / labels / hard_pos^2 into LDS (smem reuse after K-loop)
    float* sqnA = (float*)smem;
    float* sqnB = sqnA + 128;
    int* labA = (int*)(sqnB + 128);
    int* labB = labA + 128;
    float* hpA2 = (float*)(labB + 128);
    float* hpB2 = hpA2 + 128;
    if (t < 128) {
        sqnA[t] = sqn[i0 + t];
        labA[t] = lsel[i0 + t];
        hpA2[t] = __uint_as_float(hp_g[i0 + t]);
    } else {
        int u = t - 128;
        sqnB[u] = sqn[j0 + u];
        labB[u] = lsel[j0 + u];
        hpB2[u] = __uint_as_float(hp_g[j0 + u]);
    }
    __syncthreads();

    // squared distances; C/D map: col = lane&15, row = (lane>>4)*4+reg.
    // Padding rows have sqn=+INF -> dsq=+INF -> no-op in every min below.
    const float INF = __builtin_inff();
    float dsq[4][4][4];
    int colL[4], ljv[4];
    float sBv[4];
    #pragma unroll
    for (int q = 0; q < 4; q++) {
        colL[q] = wn * 64 + q * 16 + lr;
        ljv[q] = labB[colL[q]];
        sBv[q] = sqnB[colL[q]];
    }
    #pragma unroll
    for (int p = 0; p < 4; p++) {
        #pragma unroll
        for (int r = 0; r < 4; r++) {
            int rowL = wm * 64 + p * 16 + lq * 4 + r;
            float smi = sqnA[rowL];
            #pragma unroll
            for (int q = 0; q < 4; q++)
                dsq[p][q][r] = fmaxf(smi + sBv[q] - 2.f * acc[p][q][r], 0.f);
        }
    }

    // row-direction: neg_min + semi-hard min (DPP row_shl; result in lr==0)
    #pragma unroll
    for (int p = 0; p < 4; p++) {
        #pragma unroll
        for (int r = 0; r < 4; r++) {
            int rowL = wm * 64 + p * 16 + lq * 4 + r;
            int li = labA[rowL];
            float hpr = hpA2[rowL];
            float nmv = INF, smv = INF;
            #pragma unroll
            for (int q = 0; q < 4; q++) {
                float d = dsq[p][q][r];
                if (ljv[q] != li) {
                    nmv = fminf(nmv, d);
                    if (d > hpr) smv = fminf(smv, d);
                }
            }
            nmv = rmin16(nmv);
            smv = rmin16(smv);
            if (lr == 0) {
                if (nmv < INF) atomicMax(&nm_g[i0 + rowL], ~__float_as_uint(nmv));
                if (smv < INF) atomicMax(&shn_g[i0 + rowL], ~__float_as_uint(smv));
            }
        }
    }

    // column-direction (mirror; off-diagonal blocks only)
    if (!diag) {
        #pragma unroll
        for (int q = 0; q < 4; q++) {
            int lj = ljv[q];
            float hpc = hpB2[colL[q]];
            float nmv = INF, smv = INF;
            #pragma unroll
            for (int p = 0; p < 4; p++)
                #pragma unroll
                for (int r = 0; r < 4; r++) {
                    int rowL = wm * 64 + p * 16 + lq * 4 + r;
                    float d = dsq[p][q][r];
                    if (labA[rowL] != lj) {
                        nmv = fminf(nmv, d);
                        if (d > hpc) smv = fminf(smv, d);
                    }
                }
            nmv = fminf(nmv, __shfl_xor(nmv, 16));
            nmv = fminf(nmv, __shfl_xor(nmv, 32));
            smv = fminf(smv, __shfl_xor(smv, 16));
            smv = fminf(smv, __shfl_xor(smv, 32));
            if (lq == 0) {
                if (nmv < INF) atomicMax(&nm_g[j0 + colL[q]], ~__float_as_uint(nmv));
                if (smv < INF) atomicMax(&shn_g[j0 + colL[q]], ~__float_as_uint(smv));
            }
        }
    }
}

// ---------------------------------------------------------------------------
// loss reduction + final output (last finished block writes out; ctrl[7])
__global__ __launch_bounds__(256) void k_loss(const unsigned* __restrict__ hp,
                                              const unsigned* __restrict__ nm,
                                              const unsigned* __restrict__ shn,
                                              const int* __restrict__ lsel,
                                              const unsigned* __restrict__ labhist,
                                              int ksel, float* __restrict__ fsums,
                                              unsigned* __restrict__ ctrl,
                                              float* __restrict__ out) {
    __shared__ float ssum[256], scnt[256];
    int t = threadIdx.x;
    int i = blockIdx.x * 256 + t;
    float sum = 0.f, cnt = 0.f;
    if (i < ksel) {
        int li = lsel[i];
        unsigned h = labhist[li];
        bool valid = (h >= 2u) && ((unsigned)ksel > h);
        if (valid) {
            float hp2 = __uint_as_float(hp[i]);
            float nm2 = dec_min(nm[i]);
            float sh2 = dec_min(shn[i]);
            float hn2 = isinf(sh2) ? nm2 : sh2;
            sum = fmaxf(sqrtf(hp2) - sqrtf(hn2) + MARGIN, 0.f);
            cnt = 1.f;
        }
    }
    ssum[t] = sum; scnt[t] = cnt;
    __syncthreads();
    for (int off = 128; off > 0; off >>= 1) {
        if (t < off) { ssum[t] += ssum[t + off]; scnt[t] += scnt[t + off]; }
        __syncthreads();
    }
    if (t == 0) {
        atomicAdd(&fsums[0], ssum[0]);
        atomicAdd(&fsums[1], scnt[0]);
        VDRAIN();
        unsigned done = atomicAdd(&ctrl[7], 1u);
        if (done == gridDim.x - 1) {
            float s = atomicAdd(&fsums[0], 0.f);
            float c = atomicAdd(&fsums[1], 0.f);
            out[0] = (c > 0.f) ? (s / fmaxf(c, 1.f)) : 0.f;
        }
    }
}

__global__ void k_wsfail(float* out, float code) { out[0] = code; }

// ---------------------------------------------------------------------------
static inline size_t align_up(size_t x, size_t a) { return (x + a - 1) & ~(a - 1); }

extern "C" void kernel_launch(void* const* d_in, const int* in_sizes, int n_in,
                              void* d_out, int out_size, void* d_ws, size_t ws_size,
                              hipStream_t stream) {
    const float* emb  = (const float*)d_in[0];
    const int*   tags = (const int*)d_in[1];
    const float* conf = (const float*)d_in[2];
    float* out = (float*)d_out;

    int n = in_sizes[2];                        // 32768
    int ksel = (int)(0.2 * (double)n);          // 6553
    int np = ((ksel + 127) / 128) * 128;        // 6656
    int nb = np / 128;                          // 52
    int nlab = 512;                             // tags in [0,500)

    // ---- zero-init region (single hipMemsetAsync covers all of it) ----
    size_t off = 0;
    size_t o_ctrl = off; off = align_up(off + 32 * sizeof(unsigned), 256);
    size_t o_fs   = off; off = align_up(off + 8 * sizeof(float), 256);
    size_t o_lh   = off; off = align_up(off + (size_t)nlab * 4, 256);
    size_t o_hp   = off; off = align_up(off + (size_t)np * 4, 256);
    size_t o_nm   = off; off = align_up(off + (size_t)np * 4, 256);
    size_t o_shn  = off; off = align_up(off + (size_t)np * 4, 256);
    size_t zero_bytes = off;
    // ---- non-zeroed ----
    size_t o_idx  = off; off = align_up(off + (size_t)ksel * 4, 256);
    size_t o_cand = off; off = align_up(off + (size_t)n * 8, 256);
    size_t o_mem  = off; off = align_up(off + (size_t)nlab * MAXM * 4, 256);
    size_t o_lab  = off; off = align_up(off + (size_t)np * 4, 256);
    size_t o_sqn  = off; off = align_up(off + (size_t)np * 4, 256);
    size_t o_ebf  = off; off = align_up(off + (size_t)np * D * 2, 256);

    if (ws_size < off) {
        k_wsfail<<<1, 1, 0, stream>>>(out, -(float)(ws_size >> 20));
        return;
    }

    char* ws = (char*)d_ws;
    unsigned*       ctrl    = (unsigned*)(ws + o_ctrl);
    float*          fsums   = (float*)(ws + o_fs);
    unsigned*       labhist = (unsigned*)(ws + o_lh);
    unsigned*       hp_g    = (unsigned*)(ws + o_hp);
    unsigned*       nm_g    = (unsigned*)(ws + o_nm);
    unsigned*       shn_g   = (unsigned*)(ws + o_shn);
    int*            idx_sel = (int*)(ws + o_idx);
    ull*            cand    = (ull*)(ws + o_cand);
    int*            members = (int*)(ws + o_mem);
    int*            lsel    = (int*)(ws + o_lab);
    float*          sqn     = (float*)(ws + o_sqn);
    unsigned short* ebf     = (unsigned short*)(ws + o_ebf);

    hipMemsetAsync(d_ws, 0, zero_bytes, stream);
    int nhb = (n + 1023) / 1024;   // 32 blocks, fully independent (no spin)
    k_histsel<<<nhb, 1024, 0, stream>>>(conf, n, ctrl, ksel, idx_sel, cand);
    k_gather<<<np / 4, 256, 0, stream>>>(emb, tags, idx_sel, ksel, np, ebf, sqn, lsel,
                                         labhist, members);
    k_hardpos<<<512, 256, 0, stream>>>(ebf, sqn, members, labhist, hp_g);
    int ntri = nb * (nb + 1) / 2;
    k_fused<<<ntri, 256, 0, stream>>>(ebf, sqn, lsel, hp_g, nm_g, shn_g, np, nb, ksel);
    k_loss<<<(ksel + 255) / 256, 256, 0, stream>>>(hp_g, nm_g, shn_g, lsel, labhist,
                                                   ksel, fsums, ctrl, out);
}